// Round 9
// baseline (752.366 us; speedup 1.0000x reference)
//
#include <hip/hip_runtime.h>
#include <stdint.h>

#define H_DIM 4096
#define I_DIM 11008
#define T_DIM 4096

typedef int i32x4 __attribute__((ext_vector_type(4)));
typedef int i32x16 __attribute__((ext_vector_type(16)));
typedef const void __attribute__((address_space(1))) gvoid_t;
typedef void __attribute__((address_space(3))) svoid_t;

__device__ __forceinline__ void gload_lds16(const void* gsrc, void* ldst) {
    __builtin_amdgcn_global_load_lds((gvoid_t*)gsrc, (svoid_t*)ldst, 16, 0, 0);
}
__device__ __forceinline__ void wait_vmcnt8() {
    asm volatile("s_waitcnt vmcnt(8)" ::: "memory");
}
__device__ __forceinline__ void wait_vmcnt0() {
    asm volatile("s_waitcnt vmcnt(0)" ::: "memory");
}
__device__ __forceinline__ void barrier_() {
    asm volatile("s_barrier" ::: "memory");
}

__device__ __forceinline__ uint32_t pack4(int4 v) {
    uint32_t r = (uint32_t)(uint8_t)v.x;
    r |= (uint32_t)(uint8_t)v.y << 8;
    r |= (uint32_t)(uint8_t)v.z << 16;
    r |= (uint32_t)(uint8_t)v.w << 24;
    return r;
}

// int32 -> int8 pack (truncate low byte; values already int8-range)
__global__ void convert_kernel(const int* __restrict__ src, int8_t* __restrict__ dst,
                               int n4) {
    int idx = blockIdx.x * blockDim.x + threadIdx.x;
    int stride = gridDim.x * blockDim.x;
    for (int i = idx; i < n4; i += stride) {
        int4 v = ((const int4*)src)[i];
        ((uint32_t*)dst)[i] = pack4(v);
    }
}

#define MFMA32 __builtin_amdgcn_mfma_i32_32x32x32_i8

extern __shared__ int8_t smem[];

// ---------------------------------------------------------------------------
// gateup: BM=256, BN=128 (G,U), BK=128B. 512 thr, 8 waves (2Mx4N), per-wave
// 128x32 per matrix via 32x32x32 i8 MFMA (4 m-frags x 1 n-frag). R8 shell:
// 4 phases/K-tile, kk-half staging with 1.5-tile lead, vmcnt(8) at P1/P3.
// LDS 128KB: A 4x16KB halves, G 4x8KB, U 4x8KB; 64B rows, XOR swizzle.
// ---------------------------------------------------------------------------
__global__ __launch_bounds__(512, 2)
void gateup_kernel(const int8_t* __restrict__ x8, const int8_t* __restrict__ gw8,
                   const int8_t* __restrict__ uw8,
                   const float* __restrict__ galpha, const float* __restrict__ gbias,
                   const float* __restrict__ ualpha, const float* __restrict__ ubias,
                   const float* __restrict__ scale_p, int8_t* __restrict__ hq)
{
    int8_t* sA = smem;              // 4 halves x 16384
    int8_t* sG = smem + 65536;      // 4 halves x 8192
    int8_t* sU = smem + 98304;      // 4 halves x 8192

    const int bid = blockIdx.x;
    const int mt = bid & 15;        // 16 M tiles of 256 (M fastest: weight L2 reuse)
    const int nt = bid >> 4;        // 86 N tiles of 128
    const int m0 = mt << 8;
    const int n0 = nt << 7;

    const int tid  = threadIdx.x;
    const int lane = tid & 63;
    const int wid  = tid >> 6;
    const int wr   = wid >> 2;      // 0..1
    const int wc   = wid & 3;       // 0..3
    const int l31  = lane & 31;
    const int kb2  = lane >> 5;     // 0/1
    const int swz  = (l31 >> 1) & 3;

    const int srow  = tid >> 2;                          // 0..127
    const int sslot = ((tid & 3) ^ ((tid >> 3) & 3)) << 4;
    const int woff  = wid << 10;

    const int8_t* As = x8  + (size_t)(m0 + srow) * H_DIM + sslot;
    const int8_t* Gs = gw8 + (size_t)(n0 + srow) * H_DIM + sslot;
    const int8_t* Us = uw8 + (size_t)(n0 + srow) * H_DIM + sslot;

    i32x16 accg[4], accu[4];
#pragma unroll
    for (int mf = 0; mf < 4; ++mf) {
#pragma unroll
        for (int j = 0; j < 16; ++j) { accg[mf][j] = 0; accu[mf][j] = 0; }
    }

    // read-address helpers (h = half 0..3, mf = 32-row frag, kc = 32B k-chunk 0/1)
#define RD_A(h, mf, kc) (*(const i32x4*)(sA + (h) * 16384 + \
        (wr * 128 + (mf) * 32 + l31) * 64 + ((((kc) * 2 + kb2) ^ swz) << 4)))
#define RD_G(h, kc) (*(const i32x4*)(sG + (h) * 8192 + \
        (wc * 32 + l31) * 64 + ((((kc) * 2 + kb2) ^ swz) << 4)))
#define RD_U(h, kc) (*(const i32x4*)(sU + (h) * 8192 + \
        (wc * 32 + l31) * 64 + ((((kc) * 2 + kb2) ^ swz) << 4)))

#define STG_A(h, kb, c) gload_lds16(As + (size_t)(c) * 128 * H_DIM + (kb), \
                                    sA + (h) * 16384 + (c) * 8192 + woff)
#define STG_G(h, kb)    gload_lds16(Gs + (kb), sG + (h) * 8192 + woff)
#define STG_U(h, kb)    gload_lds16(Us + (kb), sU + (h) * 8192 + woff)

    const int NKT = H_DIM / 128;    // 32
    STG_A(0, 0, 0);   STG_A(0, 0, 1);   STG_G(0, 0);   STG_U(0, 0);
    STG_A(1, 64, 0);  STG_A(1, 64, 1);  STG_G(1, 64);  STG_U(1, 64);
    STG_A(2, 128, 0); STG_A(2, 128, 1); STG_G(2, 128); STG_U(2, 128);
    wait_vmcnt8();
    barrier_();

    for (int t = 0; t < NKT; ++t) {
        const int h0  = (2 * t) & 3;
        const int h1  = (2 * t + 1) & 3;
        const int hs1 = (2 * t + 3) & 3;
        const int kb1 = ((t + 1) % NKT) * 128 + 64;
        const int kb0 = ((t + 2) % NKT) * 128;
        i32x4 a00, a01, a10, a11, g0, g1, u0, u1;

        // ---- P0: h0, mf 0-1 ----
        a00 = RD_A(h0, 0, 0); a01 = RD_A(h0, 0, 1);
        a10 = RD_A(h0, 1, 0); a11 = RD_A(h0, 1, 1);
        g0 = RD_G(h0, 0); g1 = RD_G(h0, 1);
        u0 = RD_U(h0, 0); u1 = RD_U(h0, 1);
        STG_A(hs1, kb1, 0); STG_A(hs1, kb1, 1);
        barrier_();
        __builtin_amdgcn_s_setprio(1);
        accg[0] = MFMA32(a00, g0, accg[0], 0, 0, 0);
        accg[0] = MFMA32(a01, g1, accg[0], 0, 0, 0);
        accu[0] = MFMA32(a00, u0, accu[0], 0, 0, 0);
        accu[0] = MFMA32(a01, u1, accu[0], 0, 0, 0);
        accg[1] = MFMA32(a10, g0, accg[1], 0, 0, 0);
        accg[1] = MFMA32(a11, g1, accg[1], 0, 0, 0);
        accu[1] = MFMA32(a10, u0, accu[1], 0, 0, 0);
        accu[1] = MFMA32(a11, u1, accu[1], 0, 0, 0);
        __builtin_amdgcn_s_setprio(0);
        barrier_();

        // ---- P1: h0, mf 2-3 (reuse g,u) ----
        a00 = RD_A(h0, 2, 0); a01 = RD_A(h0, 2, 1);
        a10 = RD_A(h0, 3, 0); a11 = RD_A(h0, 3, 1);
        STG_G(hs1, kb1); STG_U(hs1, kb1);
        wait_vmcnt8();
        barrier_();
        __builtin_amdgcn_s_setprio(1);
        accg[2] = MFMA32(a00, g0, accg[2], 0, 0, 0);
        accg[2] = MFMA32(a01, g1, accg[2], 0, 0, 0);
        accu[2] = MFMA32(a00, u0, accu[2], 0, 0, 0);
        accu[2] = MFMA32(a01, u1, accu[2], 0, 0, 0);
        accg[3] = MFMA32(a10, g0, accg[3], 0, 0, 0);
        accg[3] = MFMA32(a11, g1, accg[3], 0, 0, 0);
        accu[3] = MFMA32(a10, u0, accu[3], 0, 0, 0);
        accu[3] = MFMA32(a11, u1, accu[3], 0, 0, 0);
        __builtin_amdgcn_s_setprio(0);
        barrier_();

        // ---- P2: h1, mf 0-1 ----
        a00 = RD_A(h1, 0, 0); a01 = RD_A(h1, 0, 1);
        a10 = RD_A(h1, 1, 0); a11 = RD_A(h1, 1, 1);
        g0 = RD_G(h1, 0); g1 = RD_G(h1, 1);
        u0 = RD_U(h1, 0); u1 = RD_U(h1, 1);
        STG_A(h0, kb0, 0); STG_A(h0, kb0, 1);
        barrier_();
        __builtin_amdgcn_s_setprio(1);
        accg[0] = MFMA32(a00, g0, accg[0], 0, 0, 0);
        accg[0] = MFMA32(a01, g1, accg[0], 0, 0, 0);
        accu[0] = MFMA32(a00, u0, accu[0], 0, 0, 0);
        accu[0] = MFMA32(a01, u1, accu[0], 0, 0, 0);
        accg[1] = MFMA32(a10, g0, accg[1], 0, 0, 0);
        accg[1] = MFMA32(a11, g1, accg[1], 0, 0, 0);
        accu[1] = MFMA32(a10, u0, accu[1], 0, 0, 0);
        accu[1] = MFMA32(a11, u1, accu[1], 0, 0, 0);
        __builtin_amdgcn_s_setprio(0);
        barrier_();

        // ---- P3: h1, mf 2-3 ----
        a00 = RD_A(h1, 2, 0); a01 = RD_A(h1, 2, 1);
        a10 = RD_A(h1, 3, 0); a11 = RD_A(h1, 3, 1);
        STG_G(h0, kb0); STG_U(h0, kb0);
        wait_vmcnt8();
        barrier_();
        __builtin_amdgcn_s_setprio(1);
        accg[2] = MFMA32(a00, g0, accg[2], 0, 0, 0);
        accg[2] = MFMA32(a01, g1, accg[2], 0, 0, 0);
        accu[2] = MFMA32(a00, u0, accu[2], 0, 0, 0);
        accu[2] = MFMA32(a01, u1, accu[2], 0, 0, 0);
        accg[3] = MFMA32(a10, g0, accg[3], 0, 0, 0);
        accg[3] = MFMA32(a11, g1, accg[3], 0, 0, 0);
        accu[3] = MFMA32(a10, u0, accu[3], 0, 0, 0);
        accu[3] = MFMA32(a11, u1, accu[3], 0, 0, 0);
        __builtin_amdgcn_s_setprio(0);
        barrier_();
    }
#undef RD_A
#undef RD_G
#undef RD_U
#undef STG_A
#undef STG_G
#undef STG_U
    wait_vmcnt0();

    // ---- epilogue: dequant, SwiGLU, requant. 32x32 C/D layout:
    // col = lane&31, row = (j&3) + 8*(j>>2) + 4*(lane>>5)  [m74/m101 verified]
    const float scale = *scale_p;
    const int col = n0 + wc * 32 + l31;
    const float gA = galpha[col], gB = gbias[col];
    const float uA = ualpha[col], uB = ubias[col];
#pragma unroll
    for (int mf = 0; mf < 4; ++mf) {
        const int rbase = m0 + wr * 128 + mf * 32 + 4 * kb2;
#pragma unroll
        for (int j = 0; j < 16; ++j) {
            const int row = rbase + (j & 3) + 8 * (j >> 2);
            float g = (float)accg[mf][j] * gA + gB;
            float u = (float)accu[mf][j] * uA + uB;
            float s = 1.0f / (1.0f + __expf(-g));
            float h = g * s * u;
            float q = rintf(h / scale);
            q = fminf(127.0f, fmaxf(-128.0f, q));
            hq[(size_t)row * I_DIM + col] = (int8_t)q;
        }
    }
}

// ---------------------------------------------------------------------------
// down: BM=256, BN=256, BK=128B. 8 waves (2Mx4N), per-wave 128x64 via
// 32x32x32 (4 m-frags x 2 n-frags). Same 4-phase shell.
// ---------------------------------------------------------------------------
__global__ __launch_bounds__(512, 2)
void down_kernel(const int8_t* __restrict__ hq, const int8_t* __restrict__ dw8,
                 const float* __restrict__ dalpha, const float* __restrict__ dbias,
                 float* __restrict__ out)
{
    int8_t* sA = smem;              // 4 halves x 16384
    int8_t* sB = smem + 65536;      // 4 halves x 16384

    const int bid = blockIdx.x;
    const int mt = bid & 15;
    const int nt = bid >> 4;
    const int m0 = mt << 8;
    const int n0 = nt << 8;

    const int tid  = threadIdx.x;
    const int lane = tid & 63;
    const int wid  = tid >> 6;
    const int wr   = wid >> 2;
    const int wc   = wid & 3;
    const int l31  = lane & 31;
    const int kb2  = lane >> 5;
    const int swz  = (l31 >> 1) & 3;

    const int srow  = tid >> 2;
    const int sslot = ((tid & 3) ^ ((tid >> 3) & 3)) << 4;
    const int woff  = wid << 10;

    const int8_t* Ap = hq  + (size_t)(m0 + srow) * I_DIM + sslot;
    const int8_t* Bp = dw8 + (size_t)(n0 + srow) * I_DIM + sslot;

    i32x16 acc[4][2];
#pragma unroll
    for (int mf = 0; mf < 4; ++mf)
#pragma unroll
        for (int nf = 0; nf < 2; ++nf)
#pragma unroll
            for (int j = 0; j < 16; ++j) acc[mf][nf][j] = 0;

#define RD_A(h, mf, kc) (*(const i32x4*)(sA + (h) * 16384 + \
        (wr * 128 + (mf) * 32 + l31) * 64 + ((((kc) * 2 + kb2) ^ swz) << 4)))
#define RD_B(h, nf, kc) (*(const i32x4*)(sB + (h) * 16384 + \
        (wc * 64 + (nf) * 32 + l31) * 64 + ((((kc) * 2 + kb2) ^ swz) << 4)))

#define STG_A(h, kb, c) gload_lds16(Ap + (size_t)(c) * 128 * I_DIM + (kb), \
                                    sA + (h) * 16384 + (c) * 8192 + woff)
#define STG_B(h, kb, c) gload_lds16(Bp + (size_t)(c) * 128 * I_DIM + (kb), \
                                    sB + (h) * 16384 + (c) * 8192 + woff)

    const int NKT = I_DIM / 128;    // 86
    STG_A(0, 0, 0);   STG_A(0, 0, 1);   STG_B(0, 0, 0);   STG_B(0, 0, 1);
    STG_A(1, 64, 0);  STG_A(1, 64, 1);  STG_B(1, 64, 0);  STG_B(1, 64, 1);
    STG_A(2, 128, 0); STG_A(2, 128, 1); STG_B(2, 128, 0); STG_B(2, 128, 1);
    wait_vmcnt8();
    barrier_();

    for (int t = 0; t < NKT; ++t) {
        const int h0  = (2 * t) & 3;
        const int h1  = (2 * t + 1) & 3;
        const int hs1 = (2 * t + 3) & 3;
        const int kb1 = ((t + 1) % NKT) * 128 + 64;
        const int kb0 = ((t + 2) % NKT) * 128;
        i32x4 a00, a01, a10, a11, b00, b01, b10, b11;

        // ---- P0: h0, mf 0-1 ----
        a00 = RD_A(h0, 0, 0); a01 = RD_A(h0, 0, 1);
        a10 = RD_A(h0, 1, 0); a11 = RD_A(h0, 1, 1);
        b00 = RD_B(h0, 0, 0); b01 = RD_B(h0, 0, 1);
        b10 = RD_B(h0, 1, 0); b11 = RD_B(h0, 1, 1);
        STG_A(hs1, kb1, 0); STG_A(hs1, kb1, 1);
        barrier_();
        __builtin_amdgcn_s_setprio(1);
        acc[0][0] = MFMA32(a00, b00, acc[0][0], 0, 0, 0);
        acc[0][0] = MFMA32(a01, b01, acc[0][0], 0, 0, 0);
        acc[0][1] = MFMA32(a00, b10, acc[0][1], 0, 0, 0);
        acc[0][1] = MFMA32(a01, b11, acc[0][1], 0, 0, 0);
        acc[1][0] = MFMA32(a10, b00, acc[1][0], 0, 0, 0);
        acc[1][0] = MFMA32(a11, b01, acc[1][0], 0, 0, 0);
        acc[1][1] = MFMA32(a10, b10, acc[1][1], 0, 0, 0);
        acc[1][1] = MFMA32(a11, b11, acc[1][1], 0, 0, 0);
        __builtin_amdgcn_s_setprio(0);
        barrier_();

        // ---- P1: h0, mf 2-3 (reuse b) ----
        a00 = RD_A(h0, 2, 0); a01 = RD_A(h0, 2, 1);
        a10 = RD_A(h0, 3, 0); a11 = RD_A(h0, 3, 1);
        STG_B(hs1, kb1, 0); STG_B(hs1, kb1, 1);
        wait_vmcnt8();
        barrier_();
        __builtin_amdgcn_s_setprio(1);
        acc[2][0] = MFMA32(a00, b00, acc[2][0], 0, 0, 0);
        acc[2][0] = MFMA32(a01, b01, acc[2][0], 0, 0, 0);
        acc[2][1] = MFMA32(a00, b10, acc[2][1], 0, 0, 0);
        acc[2][1] = MFMA32(a01, b11, acc[2][1], 0, 0, 0);
        acc[3][0] = MFMA32(a10, b00, acc[3][0], 0, 0, 0);
        acc[3][0] = MFMA32(a11, b01, acc[3][0], 0, 0, 0);
        acc[3][1] = MFMA32(a10, b10, acc[3][1], 0, 0, 0);
        acc[3][1] = MFMA32(a11, b11, acc[3][1], 0, 0, 0);
        __builtin_amdgcn_s_setprio(0);
        barrier_();

        // ---- P2: h1, mf 0-1 ----
        a00 = RD_A(h1, 0, 0); a01 = RD_A(h1, 0, 1);
        a10 = RD_A(h1, 1, 0); a11 = RD_A(h1, 1, 1);
        b00 = RD_B(h1, 0, 0); b01 = RD_B(h1, 0, 1);
        b10 = RD_B(h1, 1, 0); b11 = RD_B(h1, 1, 1);
        STG_A(h0, kb0, 0); STG_A(h0, kb0, 1);
        barrier_();
        __builtin_amdgcn_s_setprio(1);
        acc[0][0] = MFMA32(a00, b00, acc[0][0], 0, 0, 0);
        acc[0][0] = MFMA32(a01, b01, acc[0][0], 0, 0, 0);
        acc[0][1] = MFMA32(a00, b10, acc[0][1], 0, 0, 0);
        acc[0][1] = MFMA32(a01, b11, acc[0][1], 0, 0, 0);
        acc[1][0] = MFMA32(a10, b00, acc[1][0], 0, 0, 0);
        acc[1][0] = MFMA32(a11, b01, acc[1][0], 0, 0, 0);
        acc[1][1] = MFMA32(a10, b10, acc[1][1], 0, 0, 0);
        acc[1][1] = MFMA32(a11, b11, acc[1][1], 0, 0, 0);
        __builtin_amdgcn_s_setprio(0);
        barrier_();

        // ---- P3: h1, mf 2-3 ----
        a00 = RD_A(h1, 2, 0); a01 = RD_A(h1, 2, 1);
        a10 = RD_A(h1, 3, 0); a11 = RD_A(h1, 3, 1);
        STG_B(h0, kb0, 0); STG_B(h0, kb0, 1);
        wait_vmcnt8();
        barrier_();
        __builtin_amdgcn_s_setprio(1);
        acc[2][0] = MFMA32(a00, b00, acc[2][0], 0, 0, 0);
        acc[2][0] = MFMA32(a01, b01, acc[2][0], 0, 0, 0);
        acc[2][1] = MFMA32(a00, b10, acc[2][1], 0, 0, 0);
        acc[2][1] = MFMA32(a01, b11, acc[2][1], 0, 0, 0);
        acc[3][0] = MFMA32(a10, b00, acc[3][0], 0, 0, 0);
        acc[3][0] = MFMA32(a11, b01, acc[3][0], 0, 0, 0);
        acc[3][1] = MFMA32(a10, b10, acc[3][1], 0, 0, 0);
        acc[3][1] = MFMA32(a11, b11, acc[3][1], 0, 0, 0);
        __builtin_amdgcn_s_setprio(0);
        barrier_();
    }
#undef RD_A
#undef RD_B
#undef STG_A
#undef STG_B
    wait_vmcnt0();

    // ---- epilogue: dequant to fp32 (32x32 C/D layout) ----
#pragma unroll
    for (int nf = 0; nf < 2; ++nf) {
        const int col = n0 + wc * 64 + nf * 32 + l31;
        const float dA = dalpha[col], dB = dbias[col];
#pragma unroll
        for (int mf = 0; mf < 4; ++mf) {
            const int rbase = m0 + wr * 128 + mf * 32 + 4 * kb2;
#pragma unroll
            for (int j = 0; j < 16; ++j) {
                const int row = rbase + (j & 3) + 8 * (j >> 2);
                out[(size_t)row * H_DIM + col] = (float)acc[mf][nf][j] * dA + dB;
            }
        }
    }
}

extern "C" void kernel_launch(void* const* d_in, const int* in_sizes, int n_in,
                              void* d_out, int out_size, void* d_ws, size_t ws_size,
                              hipStream_t stream) {
    const int* x32  = (const int*)d_in[0];
    const int* gw32 = (const int*)d_in[1];
    const int* uw32 = (const int*)d_in[2];
    const int* dw32 = (const int*)d_in[3];
    const float* ga = (const float*)d_in[4];
    const float* gb = (const float*)d_in[5];
    const float* ua = (const float*)d_in[6];
    const float* ub = (const float*)d_in[7];
    const float* da = (const float*)d_in[8];
    const float* db = (const float*)d_in[9];
    const float* sc = (const float*)d_in[10];
    float* out = (float*)d_out;

    const size_t SZ_X8 = (size_t)T_DIM * H_DIM;
    const size_t SZ_W  = (size_t)I_DIM * H_DIM;
    const size_t SZ_HQ = (size_t)T_DIM * I_DIM;

    int8_t* gw8 = (int8_t*)d_ws;              // reused for dw8 later
    int8_t* uw8 = gw8 + SZ_W;
    int8_t* hq  = uw8 + SZ_W;
    int8_t* x8  = hq + SZ_HQ;

    hipFuncSetAttribute((const void*)gateup_kernel,
                        hipFuncAttributeMaxDynamicSharedMemorySize, 131072);
    hipFuncSetAttribute((const void*)down_kernel,
                        hipFuncAttributeMaxDynamicSharedMemorySize, 131072);

    convert_kernel<<<dim3(2048), dim3(256), 0, stream>>>(x32, x8, (int)(SZ_X8 / 4));
    convert_kernel<<<dim3(2048), dim3(256), 0, stream>>>(gw32, gw8, (int)(SZ_W / 4));
    convert_kernel<<<dim3(2048), dim3(256), 0, stream>>>(uw32, uw8, (int)(SZ_W / 4));
    gateup_kernel<<<dim3(16 * 86), dim3(512), 131072, stream>>>(
        x8, gw8, uw8, ga, gb, ua, ub, sc, hq);
    int8_t* dw8 = gw8;   // overwrite gate weights (stream-ordered after gateup)
    convert_kernel<<<dim3(2048), dim3(256), 0, stream>>>(dw32, dw8, (int)(SZ_W / 4));
    down_kernel<<<dim3(16 * 16), dim3(512), 131072, stream>>>(hq, dw8, da, db, out);
}

// Round 10
// 715.056 us; speedup vs baseline: 1.0522x; 1.0522x over previous
//
#include <hip/hip_runtime.h>
#include <stdint.h>

#define H_DIM 4096
#define I_DIM 11008
#define T_DIM 4096

typedef int i32x4 __attribute__((ext_vector_type(4)));
typedef const void __attribute__((address_space(1))) gvoid_t;
typedef void __attribute__((address_space(3))) svoid_t;

__device__ __forceinline__ void gload_lds16(const void* gsrc, void* ldst) {
    __builtin_amdgcn_global_load_lds((gvoid_t*)gsrc, (svoid_t*)ldst, 16, 0, 0);
}
__device__ __forceinline__ void wait_vmcnt3() {
    asm volatile("s_waitcnt vmcnt(3)" ::: "memory");
}
__device__ __forceinline__ void wait_vmcnt0() {
    asm volatile("s_waitcnt vmcnt(0)" ::: "memory");
}
__device__ __forceinline__ void wait_lgkm0() {
    asm volatile("s_waitcnt lgkmcnt(0)" ::: "memory");
    __builtin_amdgcn_sched_barrier(0);
}
__device__ __forceinline__ void barrier_() {
    asm volatile("s_barrier" ::: "memory");
}

__device__ __forceinline__ uint32_t pack4(int4 v) {
    uint32_t r = (uint32_t)(uint8_t)v.x;
    r |= (uint32_t)(uint8_t)v.y << 8;
    r |= (uint32_t)(uint8_t)v.z << 16;
    r |= (uint32_t)(uint8_t)v.w << 24;
    return r;
}

// int32 -> int8 pack (truncate low byte; values already int8-range)
__global__ void convert_kernel(const int* __restrict__ src, int8_t* __restrict__ dst,
                               int n4) {
    int idx = blockIdx.x * blockDim.x + threadIdx.x;
    int stride = gridDim.x * blockDim.x;
    for (int i = idx; i < n4; i += stride) {
        int4 v = ((const int4*)src)[i];
        ((uint32_t*)dst)[i] = pack4(v);
    }
}

#define MFMA_I8 __builtin_amdgcn_mfma_i32_16x16x64_i8

// ---------------------------------------------------------------------------
// gateup: tile 128x128, BK=64B. 512 thr / 8 waves, WAVE-SPECIALIZED:
// waves 0-3 accumulate G, waves 4-7 accumulate U (each 64x64 single-matrix,
// acc=64 regs -> 4 waves/SIMD at launch_bounds(512,4)). R6-proven pipeline:
// 2-buffer LDS (48KB), counted vmcnt(3) with 2-iter staging lead, lgkm0+
// barrier buffer recycling, proven XOR swizzle. Epilogue: U->G exchange via
// LDS (two 32KB halves), G-waves do SwiGLU+requant.
// ---------------------------------------------------------------------------
__global__ __launch_bounds__(512, 4)
void gateup_kernel(const int8_t* __restrict__ x8, const int8_t* __restrict__ gw8,
                   const int8_t* __restrict__ uw8,
                   const float* __restrict__ galpha, const float* __restrict__ gbias,
                   const float* __restrict__ ualpha, const float* __restrict__ ubias,
                   const float* __restrict__ scale_p, int8_t* __restrict__ hq)
{
    __shared__ __align__(16) int8_t smem_s[49152];
    int8_t* lsA = smem_s;            // 2 bufs x 8KB
    int8_t* lsG = smem_s + 16384;    // 2 bufs x 8KB
    int8_t* lsU = smem_s + 32768;    // 2 bufs x 8KB

    const int bid = blockIdx.x;
    const int mt = bid & 31;         // 32 M tiles (M fastest: weight L2 reuse)
    const int nt = bid >> 5;         // 86 N tiles
    const int m0 = mt << 7;
    const int n0 = nt << 7;

    const int tid  = threadIdx.x;
    const int lane = tid & 63;
    const int wid  = tid >> 6;       // 0..7
    const int isU  = wid >> 2;       // 0: G-wave, 1: U-wave
    const int w4   = wid & 3;
    const int wr   = w4 >> 1;        // 0..1
    const int wc   = w4 & 1;         // 0..1
    const int lr   = lane & 15;
    const int rdsw = ((lane >> 4) ^ ((lr >> 1) & 3)) << 4;  // proven swizzle

    // staging: one call = 512 thr x 16B = 128 rows x 64B (src pre-swizzled)
    const int srow = tid >> 2;                           // 0..127
    const int scol = ((tid & 3) ^ ((tid >> 3) & 3)) << 4;
    const int woff = wid << 10;

    const int8_t* As = x8  + (size_t)(m0 + srow) * H_DIM + scol;
    const int8_t* Gs = gw8 + (size_t)(n0 + srow) * H_DIM + scol;
    const int8_t* Us = uw8 + (size_t)(n0 + srow) * H_DIM + scol;

    i32x4 acc[4][4];
#pragma unroll
    for (int mf = 0; mf < 4; ++mf)
#pragma unroll
        for (int nf = 0; nf < 4; ++nf) acc[mf][nf] = i32x4{0, 0, 0, 0};

    const int aro = (wr * 64 + lr) * 64 + rdsw;    // + mf*1024
    const int bro = (wc * 64 + lr) * 64 + rdsw;    // + nf*1024
    const int8_t* myB = isU ? lsU : lsG;           // wave-uniform

#define STAGE3(b, kb) do { \
        gload_lds16(As + (kb), lsA + (b) * 8192 + woff); \
        gload_lds16(Gs + (kb), lsG + (b) * 8192 + woff); \
        gload_lds16(Us + (kb), lsU + (b) * 8192 + woff); \
    } while (0)

    const int NKT = H_DIM / 64;      // 64
    STAGE3(0, 0);
    STAGE3(1, 64);                   // 6 loads in flight per wave

    for (int t = 0; t < NKT; ++t) {
        const int cur = t & 1;
        wait_vmcnt3();               // tile-t loads landed (2-iter lead)
        barrier_();
        i32x4 af[4], bf[4];
#pragma unroll
        for (int mf = 0; mf < 4; ++mf)
            af[mf] = *(const i32x4*)(lsA + cur * 8192 + aro + mf * 1024);
#pragma unroll
        for (int nf = 0; nf < 4; ++nf)
            bf[nf] = *(const i32x4*)(myB + cur * 8192 + bro + nf * 1024);
        wait_lgkm0();
        barrier_();                  // all waves done reading buf[cur]
        STAGE3(cur, ((t + 2) & (NKT - 1)) << 6);
#pragma unroll
        for (int mf = 0; mf < 4; ++mf)
#pragma unroll
            for (int nf = 0; nf < 4; ++nf)
                acc[mf][nf] = MFMA_I8(af[mf], bf[nf], acc[mf][nf], 0, 0, 0);
    }
#undef STAGE3
    wait_vmcnt0();                   // drain tail prefetches
    barrier_();                      // LDS now reusable for exchange

    // ---- exchange U-acc -> G-waves, SwiGLU epilogue (two 32KB halves) ----
    const float scale = *scale_p;
#pragma unroll
    for (int h = 0; h < 2; ++h) {
        if (isU) {
#pragma unroll
            for (int mf = 0; mf < 4; ++mf)
#pragma unroll
                for (int q = 0; q < 2; ++q)
                    *(i32x4*)(smem_s + w4 * 8192 + mf * 2048 + q * 1024 + lane * 16)
                        = acc[mf][h * 2 + q];
        }
        barrier_();
        if (!isU) {
#pragma unroll
            for (int q = 0; q < 2; ++q) {
                const int nf = h * 2 + q;
                const int col = n0 + wc * 64 + nf * 16 + lr;
                const float gA = galpha[col], gB = gbias[col];
                const float uA = ualpha[col], uB = ubias[col];
#pragma unroll
                for (int mf = 0; mf < 4; ++mf) {
                    i32x4 uacc = *(const i32x4*)(smem_s + w4 * 8192 + mf * 2048
                                                 + q * 1024 + lane * 16);
                    const int row0 = m0 + wr * 64 + mf * 16 + (lane >> 4) * 4;
#pragma unroll
                    for (int j = 0; j < 4; ++j) {
                        float g = (float)acc[mf][nf][j] * gA + gB;
                        float u = (float)uacc[j] * uA + uB;
                        float s = 1.0f / (1.0f + __expf(-g));
                        float hh = g * s * u;
                        float qv = rintf(hh / scale);
                        qv = fminf(127.0f, fmaxf(-128.0f, qv));
                        hq[(size_t)(row0 + j) * I_DIM + col] = (int8_t)qv;
                    }
                }
            }
        }
        barrier_();
    }
}

// ---------------------------------------------------------------------------
// down: tile 128x256, BK=64B. 512 thr / 8 waves (2M x 4N), wave = 64x64
// single acc (64 regs). Same pipeline, no exchange.
// ---------------------------------------------------------------------------
__global__ __launch_bounds__(512, 4)
void down_kernel(const int8_t* __restrict__ hq, const int8_t* __restrict__ dw8,
                 const float* __restrict__ dalpha, const float* __restrict__ dbias,
                 float* __restrict__ out)
{
    __shared__ __align__(16) int8_t smem_d[49152];
    int8_t* lsA = smem_d;            // 2 bufs x 8KB
    int8_t* lsB = smem_d + 16384;    // 2 bufs x 16KB

    const int bid = blockIdx.x;
    const int mt = bid & 31;         // 32 M tiles of 128
    const int nt = bid >> 5;         // 16 N tiles of 256
    const int m0 = mt << 7;
    const int n0 = nt << 8;

    const int tid  = threadIdx.x;
    const int lane = tid & 63;
    const int wid  = tid >> 6;
    const int wr   = wid >> 2;       // 0..1
    const int wc   = wid & 3;        // 0..3
    const int lr   = lane & 15;
    const int rdsw = ((lane >> 4) ^ ((lr >> 1) & 3)) << 4;

    const int srow = tid >> 2;
    const int scol = ((tid & 3) ^ ((tid >> 3) & 3)) << 4;
    const int woff = wid << 10;

    const int8_t* Ap = hq  + (size_t)(m0 + srow) * I_DIM + scol;
    const int8_t* Bp = dw8 + (size_t)(n0 + srow) * I_DIM + scol;

    i32x4 acc[4][4];
#pragma unroll
    for (int mf = 0; mf < 4; ++mf)
#pragma unroll
        for (int nf = 0; nf < 4; ++nf) acc[mf][nf] = i32x4{0, 0, 0, 0};

    const int aro = (wr * 64 + lr) * 64 + rdsw;    // + mf*1024
    const int bro = (wc * 64 + lr) * 64 + rdsw;    // + nf*1024

#define STAGE3(b, kb) do { \
        gload_lds16(Ap + (kb), lsA + (b) * 8192 + woff); \
        gload_lds16(Bp + (kb), lsB + (b) * 16384 + woff); \
        gload_lds16(Bp + (kb) + (size_t)128 * I_DIM, lsB + (b) * 16384 + 8192 + woff); \
    } while (0)

    const int NKT = I_DIM / 64;      // 172
    STAGE3(0, 0);
    STAGE3(1, 64);

    for (int t = 0; t < NKT; ++t) {
        const int cur = t & 1;
        wait_vmcnt3();
        barrier_();
        i32x4 af[4], bf[4];
#pragma unroll
        for (int mf = 0; mf < 4; ++mf)
            af[mf] = *(const i32x4*)(lsA + cur * 8192 + aro + mf * 1024);
#pragma unroll
        for (int nf = 0; nf < 4; ++nf)
            bf[nf] = *(const i32x4*)(lsB + cur * 16384 + bro + nf * 1024);
        wait_lgkm0();
        barrier_();
        {
            const int t2 = (t + 2 < NKT) ? (t + 2) : (t + 2 - NKT);
            STAGE3(cur, t2 * 64);
        }
#pragma unroll
        for (int mf = 0; mf < 4; ++mf)
#pragma unroll
            for (int nf = 0; nf < 4; ++nf)
                acc[mf][nf] = MFMA_I8(af[mf], bf[nf], acc[mf][nf], 0, 0, 0);
    }
#undef STAGE3
    wait_vmcnt0();

    // ---- epilogue: dequant to fp32 ----
#pragma unroll
    for (int nf = 0; nf < 4; ++nf) {
        const int col = n0 + wc * 64 + nf * 16 + lr;
        const float dA = dalpha[col], dB = dbias[col];
#pragma unroll
        for (int mf = 0; mf < 4; ++mf) {
            const int row0 = m0 + wr * 64 + mf * 16 + (lane >> 4) * 4;
#pragma unroll
            for (int j = 0; j < 4; ++j) {
                out[(size_t)(row0 + j) * H_DIM + col] = (float)acc[mf][nf][j] * dA + dB;
            }
        }
    }
}

extern "C" void kernel_launch(void* const* d_in, const int* in_sizes, int n_in,
                              void* d_out, int out_size, void* d_ws, size_t ws_size,
                              hipStream_t stream) {
    const int* x32  = (const int*)d_in[0];
    const int* gw32 = (const int*)d_in[1];
    const int* uw32 = (const int*)d_in[2];
    const int* dw32 = (const int*)d_in[3];
    const float* ga = (const float*)d_in[4];
    const float* gb = (const float*)d_in[5];
    const float* ua = (const float*)d_in[6];
    const float* ub = (const float*)d_in[7];
    const float* da = (const float*)d_in[8];
    const float* db = (const float*)d_in[9];
    const float* sc = (const float*)d_in[10];
    float* out = (float*)d_out;

    const size_t SZ_X8 = (size_t)T_DIM * H_DIM;
    const size_t SZ_W  = (size_t)I_DIM * H_DIM;
    const size_t SZ_HQ = (size_t)T_DIM * I_DIM;

    int8_t* gw8 = (int8_t*)d_ws;              // reused for dw8 later
    int8_t* uw8 = gw8 + SZ_W;
    int8_t* hq  = uw8 + SZ_W;
    int8_t* x8  = hq + SZ_HQ;

    convert_kernel<<<dim3(2048), dim3(256), 0, stream>>>(x32, x8, (int)(SZ_X8 / 4));
    convert_kernel<<<dim3(2048), dim3(256), 0, stream>>>(gw32, gw8, (int)(SZ_W / 4));
    convert_kernel<<<dim3(2048), dim3(256), 0, stream>>>(uw32, uw8, (int)(SZ_W / 4));
    gateup_kernel<<<dim3(32 * 86), dim3(512), 0, stream>>>(
        x8, gw8, uw8, ga, gb, ua, ub, sc, hq);
    int8_t* dw8 = gw8;   // overwrite gate weights (stream-ordered after gateup)
    convert_kernel<<<dim3(2048), dim3(256), 0, stream>>>(dw32, dw8, (int)(SZ_W / 4));
    down_kernel<<<dim3(32 * 16), dim3(512), 0, stream>>>(hq, dw8, da, db, out);
}